// Round 10
// baseline (195.346 us; speedup 1.0000x reference)
//
#include <hip/hip_runtime.h>

#define DM 1024
#define SEQ 2048
#define NH 16
#define DH 64
#define BATCH 2

typedef _Float16 half_t;
typedef _Float16 half8 __attribute__((ext_vector_type(8)));
typedef _Float16 half4 __attribute__((ext_vector_type(4)));
typedef __fp16 f16x2 __attribute__((ext_vector_type(2)));
typedef unsigned u32x2 __attribute__((ext_vector_type(2)));
typedef unsigned u32x4 __attribute__((ext_vector_type(4)));
typedef float f32x4 __attribute__((ext_vector_type(4)));

__device__ __forceinline__ f32x4 mfma16(half8 a, half8 b, f32x4 c) {
  return __builtin_amdgcn_mfma_f32_16x16x32_f16(a, b, c, 0, 0, 0);
}
// legacy K=16 shape: A[row=l16][k=quad*4+j], B[col=l16][k=quad*4+j],
// D[col=l16][row=quad*4+r] -- A-frag layout matches swapped-QK^T output.
__device__ __forceinline__ f32x4 mfma16k16(half4 a, half4 b, f32x4 c) {
  return __builtin_amdgcn_mfma_f32_16x16x16f16(a, b, c, 0, 0, 0);
}

// async global->LDS, 16B per lane. LDS dest must be wave-uniform base + lane*16.
__device__ __forceinline__ void gl2lds16(const half_t* g, half_t* l) {
  __builtin_amdgcn_global_load_lds((const __attribute__((address_space(1))) void*)g,
                                   (__attribute__((address_space(3))) void*)l, 16, 0, 0);
}

// ---------------- merged prep kernel ----------------
// One dispatch replaces cvt_x / wtrans / ropetab (3 independent jobs).
//   [0,4096)     : x f32 -> f16
//   [4096,8192)  : weight transpose+cvt, 4 matrices x 32x32 tiles
//   [8192,8448)  : rope sin/cos tables

__global__ __launch_bounds__(256)
void prep_kernel(const float* __restrict__ x,
                 const float* __restrict__ w0, const float* __restrict__ w1,
                 const float* __restrict__ w2, const float* __restrict__ w3,
                 half_t* __restrict__ xh,
                 half_t* __restrict__ o0, half_t* __restrict__ o1,
                 half_t* __restrict__ o2, half_t* __restrict__ o3,
                 float* __restrict__ st, float* __restrict__ ct) {
  __shared__ float tile[32][33];
  const int lid = blockIdx.x;
  const int tid = threadIdx.x;
  if (lid < 4096) {
    int i = (lid * 256 + tid) * 4;
    float4 v = *(const float4*)(x + i);
    half4 h = { (half_t)v.x, (half_t)v.y, (half_t)v.z, (half_t)v.w };
    *(half4*)(xh + i) = h;
  } else if (lid < 8192) {
    int l = lid - 4096;
    int z = l >> 10;
    int by = (l >> 5) & 31, bx = l & 31;
    const float* w = (z == 0) ? w0 : (z == 1) ? w1 : (z == 2) ? w2 : w3;
    half_t* o = (z == 0) ? o0 : (z == 1) ? o1 : (z == 2) ? o2 : o3;
    int tx = tid & 31, ty0 = tid >> 5;
    int bxx = bx * 32, byy = by * 32;
#pragma unroll
    for (int i = 0; i < 4; i++) {
      int ty = ty0 + i * 8;
      tile[ty][tx] = w[(size_t)(byy + ty) * DM + bxx + tx];
    }
    __syncthreads();
#pragma unroll
    for (int i = 0; i < 4; i++) {
      int ty = ty0 + i * 8;
      o[(size_t)(bxx + ty) * DM + byy + tx] = (half_t)tile[tx][ty];
    }
  } else {
    int idx = (lid - 8192) * 256 + tid;  // 65536 = 2048*32
    int s = idx >> 5, i = idx & 31;
    float freq = exp2f(-(float)i * (13.287712379549449f / 32.0f));
    float ang = (float)s * freq;
    st[idx] = sinf(ang);
    ct[idx] = cosf(ang);
  }
}

// ---------------- QKV projection GEMM + bias + RoPE ----------------
// grid: (8, 32, 3) blocks of 256. Tile 128x128, BK=32, 4 waves each 64x64.
// 2-phase double-buffered pipeline; one barrier per K-step.
// Q pre-scaled by (1/sqrt(DH))*log2(e). V written TRANSPOSED [bh][d][s].

__global__ __launch_bounds__(256)
void qkv_kernel(const half_t* __restrict__ xh,
                const half_t* __restrict__ wtq, const half_t* __restrict__ wtk,
                const half_t* __restrict__ wtv,
                const float* __restrict__ bq, const float* __restrict__ bk,
                const float* __restrict__ bv,
                const float* __restrict__ st, const float* __restrict__ ctab,
                half_t* __restrict__ Qh, half_t* __restrict__ Kh, half_t* __restrict__ Vt) {
  const int tid = threadIdx.x;
  const int wid = tid >> 6, lane = tid & 63;
  const int l16 = lane & 15, quad = lane >> 4;
  const int m0 = blockIdx.y * 128, n0 = blockIdx.x * 128;
  const int g = blockIdx.z;
  const half_t* wt = (g == 0) ? wtq : (g == 1) ? wtk : wtv;
  const float* bias = (g == 0) ? bq : (g == 1) ? bk : bv;
  // As0 | As1 | Bs0 | Bs1 (8KB each); vtile(4x8KB) overlays after the K-loop
  __shared__ __align__(16) char smem[32768];
  f32x4 acc[4][4] = {};
  const int wrow = (wid >> 1) * 64, wcol = (wid & 1) * 64;

  const int ar0 = tid >> 2,          ab0 = (tid & 3) ^ ((ar0 >> 1) & 3);
  const int ar1 = (tid + 256) >> 2,  ab1 = (tid & 3) ^ ((ar1 >> 1) & 3);
  const int swz = (l16 >> 1) & 3;

  // prologue: stage k0=0 into buffer 0
  {
    half_t* As = (half_t*)smem;
    half_t* Bs = (half_t*)(smem + 16384);
    gl2lds16(&xh[(size_t)(m0 + ar0) * DM + ab0 * 8], &As[tid * 8]);
    gl2lds16(&xh[(size_t)(m0 + ar1) * DM + ab1 * 8], &As[(tid + 256) * 8]);
    gl2lds16(&wt[(size_t)(n0 + ar0) * DM + ab0 * 8], &Bs[tid * 8]);
    gl2lds16(&wt[(size_t)(n0 + ar1) * DM + ab1 * 8], &Bs[(tid + 256) * 8]);
  }
  __syncthreads();

  int cur = 0;
  for (int k0 = 0; k0 < DM; k0 += 32) {
    // phase 1: issue next tile's staging into buf^1 (in flight across compute)
    if (k0 + 32 < DM) {
      half_t* Asn = (half_t*)(smem + (cur ^ 1) * 8192);
      half_t* Bsn = (half_t*)(smem + 16384 + (cur ^ 1) * 8192);
      const int kn = k0 + 32;
      gl2lds16(&xh[(size_t)(m0 + ar0) * DM + kn + ab0 * 8], &Asn[tid * 8]);
      gl2lds16(&xh[(size_t)(m0 + ar1) * DM + kn + ab1 * 8], &Asn[(tid + 256) * 8]);
      gl2lds16(&wt[(size_t)(n0 + ar0) * DM + kn + ab0 * 8], &Bsn[tid * 8]);
      gl2lds16(&wt[(size_t)(n0 + ar1) * DM + kn + ab1 * 8], &Bsn[(tid + 256) * 8]);
    }
    // phase 2: compute current tile
    const half_t* Asc = (const half_t*)(smem + cur * 8192);
    const half_t* Bsc = (const half_t*)(smem + 16384 + cur * 8192);
    half8 a[4], b[4];
#pragma unroll
    for (int rt = 0; rt < 4; rt++)
      a[rt] = *(const half8*)&Asc[((wrow + rt * 16 + l16) * 4 + (quad ^ swz)) * 8];
#pragma unroll
    for (int ct = 0; ct < 4; ct++)
      b[ct] = *(const half8*)&Bsc[((wcol + ct * 16 + l16) * 4 + (quad ^ swz)) * 8];
#pragma unroll
    for (int rt = 0; rt < 4; rt++)
#pragma unroll
      for (int ct = 0; ct < 4; ct++)
        acc[rt][ct] = mfma16(a[rt], b[ct], acc[rt][ct]);
    __syncthreads();  // drains next-tile vmcnt (overlapped) + protects cur
    cur ^= 1;
  }

  // epilogue (loop ended with a barrier -> smem reusable as vtile)
  const int h = (n0 + wcol) >> 6;  // wave col-span (64) == one head
  const float qscale = 0.125f * 1.44269504089f;
  float bv4[4];
#pragma unroll
  for (int ct = 0; ct < 4; ct++) bv4[ct] = bias[n0 + wcol + ct * 16 + l16];

  if (g == 2) {
    // V path: per-wave transpose via LDS, 16B-unit XOR swizzle:
    //   vt[row*64 + ((col>>3 ^ (row&7))*8) + (col&7)]
    half_t* vt = (half_t*)(smem + wid * 8192);
#pragma unroll
    for (int rt = 0; rt < 4; rt++)
#pragma unroll
      for (int ct = 0; ct < 4; ct++) {
        half4 hv;
#pragma unroll
        for (int r = 0; r < 4; r++) hv[r] = (half_t)(acc[rt][ct][r] + bv4[ct]);
        int row = ct * 16 + l16;                  // d
        int colu = rt * 2 + (quad >> 1);          // s-chunk (8 halves)
        *(half4*)&vt[row * 64 + ((colu ^ (row & 7)) * 8) + (quad & 1) * 4] = hv;
      }
    const int sb = m0 + wrow;  // 64 consecutive rows, within one batch
    const int bb = sb >> 11, s0 = sb & 2047;
    half_t* dstv = Vt + (size_t)(bb * NH + h) * DH * SEQ;
#pragma unroll
    for (int i = 0; i < 8; i++) {
      int d = i * 8 + (lane >> 3), c = lane & 7;
      half8 v = *(const half8*)&vt[d * 64 + ((c ^ (d & 7)) * 8)];
      *(half8*)&dstv[(size_t)d * SEQ + s0 + c * 8] = v;
    }
  } else {
    // Q/K path: bias + RoPE (+ qscale for Q); coalesced [bh][s][d] stores
    half_t* dst = (g == 0) ? Qh : Kh;
#pragma unroll
    for (int rt = 0; rt < 4; rt++) {
#pragma unroll
      for (int r = 0; r < 4; r++) {
        int m = m0 + wrow + rt * 16 + quad * 4 + r;
        int bb = m >> 11, s = m & 2047;
        float v0 = acc[rt][0][r] + bv4[0];  // d = l16
        float v1 = acc[rt][1][r] + bv4[1];  // d = 16+l16
        float v2 = acc[rt][2][r] + bv4[2];  // d = 32+l16
        float v3 = acc[rt][3][r] + bv4[3];  // d = 48+l16
        float sn0 = st[s * 32 + l16], cs0 = ctab[s * 32 + l16];
        float sn1 = st[s * 32 + 16 + l16], cs1 = ctab[s * 32 + 16 + l16];
        float o0 = v0 * cs0 - v2 * sn0;
        float o1 = v1 * cs1 - v3 * sn1;
        float o2 = v2 * cs0 + v0 * sn0;
        float o3 = v3 * cs1 + v1 * sn1;
        if (g == 0) { o0 *= qscale; o1 *= qscale; o2 *= qscale; o3 *= qscale; }
        size_t base = ((size_t)(bb * NH + h) * SEQ + s) * DH;
        dst[base + l16]      = (half_t)o0;
        dst[base + 16 + l16] = (half_t)o1;
        dst[base + 32 + l16] = (half_t)o2;
        dst[base + 48 + l16] = (half_t)o3;
      }
    }
  }
}

// ---------------- flash attention (v9) ----------------
// Occupancy lever: 16 waves per block (1024 threads), 16 q-rows per wave.
// Same 256-block grid / XCD affinity / shared staging (KVBLK=64, staged
// ONCE per CU per tile: threads <512 stage K slots, >=512 stage V slots,
// one 16B slot each). Waves/SIMD 2 -> 4 (VGPR ~64): each wave's serial
// ds_read->MFMA->exp2->cvt->MFMA chain now has 3 partners to hide under.
// Inner math identical to v5 (swapped QK^T, P-in-register K16 PV, T14).

__global__ __launch_bounds__(1024)
void attn_kernel(const half_t* __restrict__ Qh, const half_t* __restrict__ Kh,
                 const half_t* __restrict__ Vt, half_t* __restrict__ AO) {
  const int tid = threadIdx.x;
  const int wid = tid >> 6, lane = tid & 63;   // wid 0..15
  const int l16 = lane & 15, quad = lane >> 4;
  const int lid = blockIdx.x;              // 256 blocks
  const int bh = lid & 31, qt = lid >> 5;  // same-bh -> same XCD
  const int bb = bh >> 4, h = bh & 15;
  const int q0 = qt * 256 + wid * 16;      // 16 q-rows per wave
  const half_t* Q = Qh + (size_t)bh * SEQ * DH;
  const half_t* K = Kh + (size_t)bh * SEQ * DH;
  const half_t* V = Vt + (size_t)bh * DH * SEQ;
  __shared__ __align__(16) half_t Ks[2][64 * 64];
  __shared__ __align__(16) half_t Vs[2][64 * 64];

  // staging: role by tid<512 (K) / >=512 (V); one 16B slot per thread.
  // slot s -> row s>>3, XOR-swizzled chunk (s&7)^(row&7). Per-wave lanes are
  // consecutive slots -> LDS dest = wave-uniform base + lane*16B (gl2lds ok).
  const int slot = tid & 511;
  const int sr = slot >> 3, sc = (slot & 7) ^ (sr & 7);
  const bool isK = (tid < 512);
  const half_t* gptr = isK ? &K[(size_t)sr * DH + sc * 8]
                           : &V[(size_t)sr * SEQ + sc * 8];
  const int ginc = isK ? 64 * DH : 64;     // advance one 64-k tile
  half_t* lbase = (isK ? &Ks[0][0] : &Vs[0][0]) + slot * 8;  // buf stride 4096

  // swizzled K ds_read chunk offsets (halves) for d-chunks quad, quad+4
  const int sw0 = ((quad ^ (l16 & 7)) * 8);
  const int sw1 = (((quad + 4) ^ (l16 & 7)) * 8);

  // Q fragments: lane holds Q[q0+l16][quad*8+j] (+32 for the hi d-chunk)
  half8 aqA = *(const half8*)&Q[(size_t)(q0 + l16) * DH + quad * 8];
  half8 aqB = *(const half8*)&Q[(size_t)(q0 + l16) * DH + 32 + quad * 8];

  f32x4 o[4] = {};
  f32x4 vsum = {};
  const f32x4 cinit = {-12.f, -12.f, -12.f, -12.f};

  // prologue: stage tile 0 into buffer 0 (async; barrier drains vmcnt)
  gl2lds16(gptr, lbase);
  gptr += ginc;
  __syncthreads();

  int cur = 0;
  for (int kb0 = 0; kb0 < SEQ; kb0 += 64) {
    const bool pf = (kb0 + 64 < SEQ);
    // T14 phase 1: issue next tile's global load into a register NOW.
    u32x4 rg;
    if (pf) rg = *(const u32x4*)gptr;
    const half_t* ksrc = Ks[cur];
    const half_t* vsrc = Vs[cur];

    // QK^T swapped: A = K rows, B = Q rows.
    // z[kt][r] = S[q=q0+l16][k=kb0+kt*16+quad*4+r] - 12
    f32x4 z[4];
#pragma unroll
    for (int kt = 0; kt < 4; kt++) {
      const half_t* krow = &ksrc[(kt * 16 + l16) * 64];
      half8 b0 = *(const half8*)&krow[sw0];
      half8 b1 = *(const half8*)&krow[sw1];
      f32x4 zz = cinit;
      zz = mfma16(b0, aqA, zz);
      zz = mfma16(b1, aqB, zz);
      z[kt] = zz;
    }

    // softmax: exp2, f32 row-sum, packed f16 convert -> pa[kt] is the READY
    // A-fragment for the K=16 PV MFMA (k = kt*16 + quad*4 + j).
    half4 pa[4];
#pragma unroll
    for (int kt = 0; kt < 4; kt++) {
      f32x4 p;
#pragma unroll
      for (int r = 0; r < 4; r++) p[r] = __builtin_amdgcn_exp2f(z[kt][r]);
      vsum += p;
      f16x2 lo = __builtin_amdgcn_cvt_pkrtz(p[0], p[1]);
      f16x2 hi = __builtin_amdgcn_cvt_pkrtz(p[2], p[3]);
      u32x2 w = { __builtin_bit_cast(unsigned, lo), __builtin_bit_cast(unsigned, hi) };
      pa[kt] = __builtin_bit_cast(half4, w);
    }

    // PV: o[d] += P * V. B-frag = V[k=kt*16+quad*4+j][d=dt*16+l16], a half4
    // from swizzled Vs (V^T rows d): phys = row*64 + ((chunk ^ (row&7))*8)
    // + (quad&1)*4, chunk = kt*2 + (quad>>1).
#pragma unroll
    for (int dt = 0; dt < 4; dt++) {
      const int row = dt * 16 + l16;
      const half_t* vrow = &vsrc[row * 64 + (quad & 1) * 4];
#pragma unroll
      for (int kt = 0; kt < 4; kt++) {
        half4 bv = *(const half4*)&vrow[((kt * 2 + (quad >> 1)) ^ (l16 & 7)) * 8];
        o[dt] = mfma16k16(pa[kt], bv, o[dt]);
      }
    }

    // T14 phase 2: vmcnt wait (first use of rg) lands HERE, after compute.
    if (pf) {
      *(u32x4*)(lbase + (cur ^ 1) * 4096) = rg;
      gptr += ginc;
    }
    __syncthreads();  // lgkm drain + buffer handoff
    cur ^= 1;
  }

  // row sums: lane has partial sum for q = q0+l16 over its k subset;
  // reduce across quads (lane bits 4,5), then fetch per-output-row inverse.
  float linv[4];
  {
    float s = (vsum[0] + vsum[1]) + (vsum[2] + vsum[3]);
    s += __shfl_xor(s, 16);
    s += __shfl_xor(s, 32);
#pragma unroll
    for (int r = 0; r < 4; r++) linv[r] = 1.f / __shfl(s, quad * 4 + r);
  }
#pragma unroll
  for (int dt = 0; dt < 4; dt++)
#pragma unroll
    for (int r = 0; r < 4; r++) {
      int srow = q0 + quad * 4 + r;
      AO[((size_t)bb * SEQ + srow) * DM + h * DH + dt * 16 + l16] =
          (half_t)(o[dt][r] * linv[r]);
    }
}

// ---------------- output projection ----------------
// Tile 128(m)x64(n), BK=32, grid (16,32) = 512 blocks (2/CU). 4 waves each
// 64x32. 2-phase double-buffered pipeline.

__global__ __launch_bounds__(256)
void out_kernel(const half_t* __restrict__ AO, const half_t* __restrict__ wto,
                const float* __restrict__ bo, float* __restrict__ out) {
  const int tid = threadIdx.x;
  const int wid = tid >> 6, lane = tid & 63;
  const int l16 = lane & 15, quad = lane >> 4;
  const int m0 = blockIdx.y * 128, n0 = blockIdx.x * 64;
  // As0(8K) | As1(8K) | Bs0(4K) | Bs1(4K)
  __shared__ __align__(16) char smem[24576];
  f32x4 acc[4][2] = {};
  const int wrow = (wid >> 1) * 64, wcol = (wid & 1) * 32;

  const int ar0 = tid >> 2,         ab0 = (tid & 3) ^ ((ar0 >> 1) & 3);
  const int ar1 = (tid + 256) >> 2, ab1 = (tid & 3) ^ ((ar1 >> 1) & 3);
  const int swz = (l16 >> 1) & 3;

  // prologue: stage k0=0 into buffer 0
  {
    half_t* As = (half_t*)smem;
    half_t* Bs = (half_t*)(smem + 16384);
    gl2lds16(&AO[(size_t)(m0 + ar0) * DM + ab0 * 8], &As[tid * 8]);
    gl2lds16(&AO[(size_t)(m0 + ar1) * DM + ab1 * 8], &As[(tid + 256) * 8]);
    gl2lds16(&wto[(size_t)(n0 + ar0) * DM + ab0 * 8], &Bs[tid * 8]);
  }
  __syncthreads();

  int cur = 0;
  for (int k0 = 0; k0 < DM; k0 += 32) {
    if (k0 + 32 < DM) {
      half_t* Asn = (half_t*)(smem + (cur ^ 1) * 8192);
      half_t* Bsn = (half_t*)(smem + 16384 + (cur ^ 1) * 4096);
      const int kn = k0 + 32;
      gl2lds16(&AO[(size_t)(m0 + ar0) * DM + kn + ab0 * 8], &Asn[tid * 8]);
      gl2lds16(&AO[(size_t)(m0 + ar1) * DM + kn + ab1 * 8], &Asn[(tid + 256) * 8]);
      gl2lds16(&wto[(size_t)(n0 + ar0) * DM + kn + ab0 * 8], &Bsn[tid * 8]);
    }
    const half_t* Asc = (const half_t*)(smem + cur * 8192);
    const half_t* Bsc = (const half_t*)(smem + 16384 + cur * 4096);
    half8 a[4], b[2];
#pragma unroll
    for (int rt = 0; rt < 4; rt++)
      a[rt] = *(const half8*)&Asc[((wrow + rt * 16 + l16) * 4 + (quad ^ swz)) * 8];
#pragma unroll
    for (int ct = 0; ct < 2; ct++)
      b[ct] = *(const half8*)&Bsc[((wcol + ct * 16 + l16) * 4 + (quad ^ swz)) * 8];
#pragma unroll
    for (int rt = 0; rt < 4; rt++)
#pragma unroll
      for (int ct = 0; ct < 2; ct++)
        acc[rt][ct] = mfma16(a[rt], b[ct], acc[rt][ct]);
    __syncthreads();
    cur ^= 1;
  }
  float bv2[2];
#pragma unroll
  for (int ct = 0; ct < 2; ct++) bv2[ct] = bo[n0 + wcol + ct * 16 + l16];
#pragma unroll
  for (int rt = 0; rt < 4; rt++)
#pragma unroll
    for (int r = 0; r < 4; r++) {
      int m = m0 + wrow + rt * 16 + quad * 4 + r;
#pragma unroll
      for (int ct = 0; ct < 2; ct++)
        out[(size_t)m * DM + n0 + wcol + ct * 16 + l16] = acc[rt][ct][r] + bv2[ct];
    }
}

// ---------------- launch ----------------

extern "C" void kernel_launch(void* const* d_in, const int* in_sizes, int n_in,
                              void* d_out, int out_size, void* d_ws, size_t ws_size,
                              hipStream_t stream) {
  (void)in_sizes; (void)n_in; (void)out_size; (void)ws_size;
  const float* x  = (const float*)d_in[0];
  const float* wq = (const float*)d_in[1];
  const float* bq = (const float*)d_in[2];
  const float* wk = (const float*)d_in[3];
  const float* bk = (const float*)d_in[4];
  const float* wv = (const float*)d_in[5];
  const float* bv = (const float*)d_in[6];
  const float* wo = (const float*)d_in[7];
  const float* bo = (const float*)d_in[8];
  char* ws = (char*)d_ws;
  const size_t MB = 1u << 20;
  // xh and AO share [0,8) MB: xh dead after qkv, AO born after attn.
  half_t* xh  = (half_t*)(ws + 0);
  half_t* AO  = (half_t*)(ws + 0);
  half_t* wtq = (half_t*)(ws + 8 * MB);
  half_t* wtk = (half_t*)(ws + 10 * MB);
  half_t* wtv = (half_t*)(ws + 12 * MB);
  half_t* wto = (half_t*)(ws + 14 * MB);
  float*  st  = (float*)(ws + 16 * MB);
  float*  ctb = (float*)(ws + 16 * MB + 256 * 1024);
  half_t* Qh  = (half_t*)(ws + 17 * MB);
  half_t* Kh  = (half_t*)(ws + 25 * MB);
  half_t* Vt  = (half_t*)(ws + 33 * MB);
  float* out = (float*)d_out;

  prep_kernel<<<8448, 256, 0, stream>>>(x, wq, wk, wv, wo, xh, wtq, wtk, wtv, wto, st, ctb);
  qkv_kernel<<<dim3(8, 32, 3), 256, 0, stream>>>(xh, wtq, wtk, wtv, bq, bk, bv, st, ctb, Qh, Kh, Vt);
  attn_kernel<<<256, 1024, 0, stream>>>(Qh, Kh, Vt, AO);
  out_kernel<<<dim3(16, 32), 256, 0, stream>>>(AO, wto, bo, out);
}

// Round 11
// 189.470 us; speedup vs baseline: 1.0310x; 1.0310x over previous
//
#include <hip/hip_runtime.h>

#define DM 1024
#define SEQ 2048
#define NH 16
#define DH 64
#define BATCH 2

typedef _Float16 half_t;
typedef _Float16 half8 __attribute__((ext_vector_type(8)));
typedef _Float16 half4 __attribute__((ext_vector_type(4)));
typedef __fp16 f16x2 __attribute__((ext_vector_type(2)));
typedef unsigned u32x2 __attribute__((ext_vector_type(2)));
typedef unsigned u32x4 __attribute__((ext_vector_type(4)));
typedef float f32x4 __attribute__((ext_vector_type(4)));

__device__ __forceinline__ f32x4 mfma16(half8 a, half8 b, f32x4 c) {
  return __builtin_amdgcn_mfma_f32_16x16x32_f16(a, b, c, 0, 0, 0);
}
// legacy K=16 shape: A[row=l16][k=quad*4+j], B[col=l16][k=quad*4+j],
// D[col=l16][row=quad*4+r] -- A-frag layout matches swapped-QK^T output.
__device__ __forceinline__ f32x4 mfma16k16(half4 a, half4 b, f32x4 c) {
  return __builtin_amdgcn_mfma_f32_16x16x16f16(a, b, c, 0, 0, 0);
}

// async global->LDS, 16B per lane. LDS dest must be wave-uniform base + lane*16.
__device__ __forceinline__ void gl2lds16(const half_t* g, half_t* l) {
  __builtin_amdgcn_global_load_lds((const __attribute__((address_space(1))) void*)g,
                                   (__attribute__((address_space(3))) void*)l, 16, 0, 0);
}

// ---------------- merged prep kernel ----------------
// One dispatch replaces cvt_x / wtrans / ropetab (3 independent jobs).
//   [0,4096)     : x f32 -> f16
//   [4096,8192)  : weight transpose+cvt, 4 matrices x 32x32 tiles
//   [8192,8448)  : rope sin/cos tables

__global__ __launch_bounds__(256)
void prep_kernel(const float* __restrict__ x,
                 const float* __restrict__ w0, const float* __restrict__ w1,
                 const float* __restrict__ w2, const float* __restrict__ w3,
                 half_t* __restrict__ xh,
                 half_t* __restrict__ o0, half_t* __restrict__ o1,
                 half_t* __restrict__ o2, half_t* __restrict__ o3,
                 float* __restrict__ st, float* __restrict__ ct) {
  __shared__ float tile[32][33];
  const int lid = blockIdx.x;
  const int tid = threadIdx.x;
  if (lid < 4096) {
    int i = (lid * 256 + tid) * 4;
    float4 v = *(const float4*)(x + i);
    half4 h = { (half_t)v.x, (half_t)v.y, (half_t)v.z, (half_t)v.w };
    *(half4*)(xh + i) = h;
  } else if (lid < 8192) {
    int l = lid - 4096;
    int z = l >> 10;
    int by = (l >> 5) & 31, bx = l & 31;
    const float* w = (z == 0) ? w0 : (z == 1) ? w1 : (z == 2) ? w2 : w3;
    half_t* o = (z == 0) ? o0 : (z == 1) ? o1 : (z == 2) ? o2 : o3;
    int tx = tid & 31, ty0 = tid >> 5;
    int bxx = bx * 32, byy = by * 32;
#pragma unroll
    for (int i = 0; i < 4; i++) {
      int ty = ty0 + i * 8;
      tile[ty][tx] = w[(size_t)(byy + ty) * DM + bxx + tx];
    }
    __syncthreads();
#pragma unroll
    for (int i = 0; i < 4; i++) {
      int ty = ty0 + i * 8;
      o[(size_t)(bxx + ty) * DM + byy + tx] = (half_t)tile[tx][ty];
    }
  } else {
    int idx = (lid - 8192) * 256 + tid;  // 65536 = 2048*32
    int s = idx >> 5, i = idx & 31;
    float freq = exp2f(-(float)i * (13.287712379549449f / 32.0f));
    float ang = (float)s * freq;
    st[idx] = sinf(ang);
    ct[idx] = cosf(ang);
  }
}

// ---------------- QKV projection GEMM + bias + RoPE ----------------
// grid: (8, 32, 3) blocks of 256. Tile 128x128, BK=32, 4 waves each 64x64.
// 2-phase double-buffered pipeline; one barrier per K-step.
// Q pre-scaled by (1/sqrt(DH))*log2(e). V written TRANSPOSED [bh][d][s].

__global__ __launch_bounds__(256)
void qkv_kernel(const half_t* __restrict__ xh,
                const half_t* __restrict__ wtq, const half_t* __restrict__ wtk,
                const half_t* __restrict__ wtv,
                const float* __restrict__ bq, const float* __restrict__ bk,
                const float* __restrict__ bv,
                const float* __restrict__ st, const float* __restrict__ ctab,
                half_t* __restrict__ Qh, half_t* __restrict__ Kh, half_t* __restrict__ Vt) {
  const int tid = threadIdx.x;
  const int wid = tid >> 6, lane = tid & 63;
  const int l16 = lane & 15, quad = lane >> 4;
  const int m0 = blockIdx.y * 128, n0 = blockIdx.x * 128;
  const int g = blockIdx.z;
  const half_t* wt = (g == 0) ? wtq : (g == 1) ? wtk : wtv;
  const float* bias = (g == 0) ? bq : (g == 1) ? bk : bv;
  // As0 | As1 | Bs0 | Bs1 (8KB each); vtile(4x8KB) overlays after the K-loop
  __shared__ __align__(16) char smem[32768];
  f32x4 acc[4][4] = {};
  const int wrow = (wid >> 1) * 64, wcol = (wid & 1) * 64;

  const int ar0 = tid >> 2,          ab0 = (tid & 3) ^ ((ar0 >> 1) & 3);
  const int ar1 = (tid + 256) >> 2,  ab1 = (tid & 3) ^ ((ar1 >> 1) & 3);
  const int swz = (l16 >> 1) & 3;

  // prologue: stage k0=0 into buffer 0
  {
    half_t* As = (half_t*)smem;
    half_t* Bs = (half_t*)(smem + 16384);
    gl2lds16(&xh[(size_t)(m0 + ar0) * DM + ab0 * 8], &As[tid * 8]);
    gl2lds16(&xh[(size_t)(m0 + ar1) * DM + ab1 * 8], &As[(tid + 256) * 8]);
    gl2lds16(&wt[(size_t)(n0 + ar0) * DM + ab0 * 8], &Bs[tid * 8]);
    gl2lds16(&wt[(size_t)(n0 + ar1) * DM + ab1 * 8], &Bs[(tid + 256) * 8]);
  }
  __syncthreads();

  int cur = 0;
  for (int k0 = 0; k0 < DM; k0 += 32) {
    // phase 1: issue next tile's staging into buf^1 (in flight across compute)
    if (k0 + 32 < DM) {
      half_t* Asn = (half_t*)(smem + (cur ^ 1) * 8192);
      half_t* Bsn = (half_t*)(smem + 16384 + (cur ^ 1) * 8192);
      const int kn = k0 + 32;
      gl2lds16(&xh[(size_t)(m0 + ar0) * DM + kn + ab0 * 8], &Asn[tid * 8]);
      gl2lds16(&xh[(size_t)(m0 + ar1) * DM + kn + ab1 * 8], &Asn[(tid + 256) * 8]);
      gl2lds16(&wt[(size_t)(n0 + ar0) * DM + kn + ab0 * 8], &Bsn[tid * 8]);
      gl2lds16(&wt[(size_t)(n0 + ar1) * DM + kn + ab1 * 8], &Bsn[(tid + 256) * 8]);
    }
    // phase 2: compute current tile
    const half_t* Asc = (const half_t*)(smem + cur * 8192);
    const half_t* Bsc = (const half_t*)(smem + 16384 + cur * 8192);
    half8 a[4], b[4];
#pragma unroll
    for (int rt = 0; rt < 4; rt++)
      a[rt] = *(const half8*)&Asc[((wrow + rt * 16 + l16) * 4 + (quad ^ swz)) * 8];
#pragma unroll
    for (int ct = 0; ct < 4; ct++)
      b[ct] = *(const half8*)&Bsc[((wcol + ct * 16 + l16) * 4 + (quad ^ swz)) * 8];
#pragma unroll
    for (int rt = 0; rt < 4; rt++)
#pragma unroll
      for (int ct = 0; ct < 4; ct++)
        acc[rt][ct] = mfma16(a[rt], b[ct], acc[rt][ct]);
    __syncthreads();  // drains next-tile vmcnt (overlapped) + protects cur
    cur ^= 1;
  }

  // epilogue (loop ended with a barrier -> smem reusable as vtile)
  const int h = (n0 + wcol) >> 6;  // wave col-span (64) == one head
  const float qscale = 0.125f * 1.44269504089f;
  float bv4[4];
#pragma unroll
  for (int ct = 0; ct < 4; ct++) bv4[ct] = bias[n0 + wcol + ct * 16 + l16];

  if (g == 2) {
    // V path: per-wave transpose via LDS, 16B-unit XOR swizzle:
    //   vt[row*64 + ((col>>3 ^ (row&7))*8) + (col&7)]
    half_t* vt = (half_t*)(smem + wid * 8192);
#pragma unroll
    for (int rt = 0; rt < 4; rt++)
#pragma unroll
      for (int ct = 0; ct < 4; ct++) {
        half4 hv;
#pragma unroll
        for (int r = 0; r < 4; r++) hv[r] = (half_t)(acc[rt][ct][r] + bv4[ct]);
        int row = ct * 16 + l16;                  // d
        int colu = rt * 2 + (quad >> 1);          // s-chunk (8 halves)
        *(half4*)&vt[row * 64 + ((colu ^ (row & 7)) * 8) + (quad & 1) * 4] = hv;
      }
    const int sb = m0 + wrow;  // 64 consecutive rows, within one batch
    const int bb = sb >> 11, s0 = sb & 2047;
    half_t* dstv = Vt + (size_t)(bb * NH + h) * DH * SEQ;
#pragma unroll
    for (int i = 0; i < 8; i++) {
      int d = i * 8 + (lane >> 3), c = lane & 7;
      half8 v = *(const half8*)&vt[d * 64 + ((c ^ (d & 7)) * 8)];
      *(half8*)&dstv[(size_t)d * SEQ + s0 + c * 8] = v;
    }
  } else {
    // Q/K path: bias + RoPE (+ qscale for Q); coalesced [bh][s][d] stores
    half_t* dst = (g == 0) ? Qh : Kh;
#pragma unroll
    for (int rt = 0; rt < 4; rt++) {
#pragma unroll
      for (int r = 0; r < 4; r++) {
        int m = m0 + wrow + rt * 16 + quad * 4 + r;
        int bb = m >> 11, s = m & 2047;
        float v0 = acc[rt][0][r] + bv4[0];  // d = l16
        float v1 = acc[rt][1][r] + bv4[1];  // d = 16+l16
        float v2 = acc[rt][2][r] + bv4[2];  // d = 32+l16
        float v3 = acc[rt][3][r] + bv4[3];  // d = 48+l16
        float sn0 = st[s * 32 + l16], cs0 = ctab[s * 32 + l16];
        float sn1 = st[s * 32 + 16 + l16], cs1 = ctab[s * 32 + 16 + l16];
        float o0 = v0 * cs0 - v2 * sn0;
        float o1 = v1 * cs1 - v3 * sn1;
        float o2 = v2 * cs0 + v0 * sn0;
        float o3 = v3 * cs1 + v1 * sn1;
        if (g == 0) { o0 *= qscale; o1 *= qscale; o2 *= qscale; o3 *= qscale; }
        size_t base = ((size_t)(bb * NH + h) * SEQ + s) * DH;
        dst[base + l16]      = (half_t)o0;
        dst[base + 16 + l16] = (half_t)o1;
        dst[base + 32 + l16] = (half_t)o2;
        dst[base + 48 + l16] = (half_t)o3;
      }
    }
  }
}

// ---------------- flash attention (v5 -- best measured, 49.0 us R6) ----------
// 8-wave blocks (512 thr), 256 q-rows/block, K/V staged once per CU per
// 64-k tile (one K slot + one V slot per thread), XCD affinity, T14
// reg-staging, swapped QK^T, P-in-register PV via K=16 MFMA, s_setprio.
// Reverted verbatim after v6 (4-wave), v7 (KVBLK128), v8 (SW-pipe),
// v9 (16-wave) all measured equal or worse (50.9/57.8/51.5/57.0).

__global__ __launch_bounds__(512)
void attn_kernel(const half_t* __restrict__ Qh, const half_t* __restrict__ Kh,
                 const half_t* __restrict__ Vt, half_t* __restrict__ AO) {
  const int tid = threadIdx.x;
  const int wid = tid >> 6, lane = tid & 63;
  const int l16 = lane & 15, quad = lane >> 4;
  const int lid = blockIdx.x;              // 256 blocks
  const int bh = lid & 31, qt = lid >> 5;  // same-bh -> same XCD
  const int bb = bh >> 4, h = bh & 15;
  const int q0 = qt * 256 + wid * 32;
  const half_t* Q = Qh + (size_t)bh * SEQ * DH;
  const half_t* K = Kh + (size_t)bh * SEQ * DH;
  const half_t* V = Vt + (size_t)bh * DH * SEQ;
  __shared__ __align__(16) half_t Ks[2][64 * 64];
  __shared__ __align__(16) half_t Vs[2][64 * 64];

  // staging slot: 512 threads x 16B = one 64x64 tile; XOR chunk swizzle
  const int r0 = tid >> 3, c0 = (tid & 7) ^ (r0 & 7);
  // swizzled ds_read chunk offsets (halves) for logical d-chunks quad, quad+4
  const int sw0 = ((quad ^ (l16 & 7)) * 8);
  const int sw1 = (((quad + 4) ^ (l16 & 7)) * 8);

  const half_t* gK0 = &K[(size_t)r0 * DH + c0 * 8];
  const half_t* gV0 = &V[(size_t)r0 * SEQ + c0 * 8];

  // Q fragments: lane holds Q[q0+rt*16+l16][quad*8+j] (+32 for B-chunk hi)
  half8 aqA[2], aqB[2];
#pragma unroll
  for (int rt = 0; rt < 2; rt++) {
    aqA[rt] = *(const half8*)&Q[(size_t)(q0 + rt * 16 + l16) * DH + quad * 8];
    aqB[rt] = *(const half8*)&Q[(size_t)(q0 + rt * 16 + l16) * DH + 32 + quad * 8];
  }

  f32x4 o[2][4] = {};
  f32x4 vsum[2] = {};
  const f32x4 cinit = {-12.f, -12.f, -12.f, -12.f};

  // prologue: stage tile 0 into buffer 0 (async; barrier drains vmcnt)
  gl2lds16(gK0, &Ks[0][tid * 8]);
  gl2lds16(gV0, &Vs[0][tid * 8]);
  __syncthreads();

  int cur = 0;
  for (int kb0 = 0; kb0 < SEQ; kb0 += 64) {
    const bool pf = (kb0 + 64 < SEQ);
    // T14 phase 1: issue next tile's global loads into registers NOW.
    u32x4 rk0, rv0;
    if (pf) {
      const int kb = kb0 + 64;
      rk0 = *(const u32x4*)(gK0 + (size_t)kb * DH);
      rv0 = *(const u32x4*)(gV0 + kb);
    }
    const half_t* ksrc = Ks[cur];
    const half_t* vsrc = Vs[cur];

    // QK^T swapped: A = K rows, B = Q rows. z[rt][kt][r] =
    // S[q = q0+rt*16+l16][k = kb0+kt*16+quad*4+r] - 12
    f32x4 z[2][4];
    __builtin_amdgcn_s_setprio(1);
#pragma unroll
    for (int kt = 0; kt < 4; kt++) {
      const half_t* krow = &ksrc[(kt * 16 + l16) * 64];
      half8 b0 = *(const half8*)&krow[sw0];
      half8 b1 = *(const half8*)&krow[sw1];
#pragma unroll
      for (int rt = 0; rt < 2; rt++) {
        f32x4 zz = cinit;
        zz = mfma16(b0, aqA[rt], zz);
        zz = mfma16(b1, aqB[rt], zz);
        z[rt][kt] = zz;
      }
    }
    __builtin_amdgcn_s_setprio(0);

    // softmax: exp2, f32 row-sum, packed f16 convert -> pa[rt][kt] is the
    // READY A-fragment for the K=16 PV MFMA (k = kt*16 + quad*4 + j).
    half4 pa[2][4];
#pragma unroll
    for (int rt = 0; rt < 2; rt++)
#pragma unroll
      for (int kt = 0; kt < 4; kt++) {
        f32x4 p;
#pragma unroll
        for (int r = 0; r < 4; r++) p[r] = __builtin_amdgcn_exp2f(z[rt][kt][r]);
        vsum[rt] += p;
        f16x2 lo = __builtin_amdgcn_cvt_pkrtz(p[0], p[1]);
        f16x2 hi = __builtin_amdgcn_cvt_pkrtz(p[2], p[3]);
        u32x2 w = { __builtin_bit_cast(unsigned, lo), __builtin_bit_cast(unsigned, hi) };
        pa[rt][kt] = __builtin_bit_cast(half4, w);
      }

    // PV: o[q][d] += P * V. B-frag = V[k=kt*16+quad*4+j][d=dt*16+l16], a
    // half4 from swizzled Vs (V^T rows d): phys = row*64 +
    // ((chunk ^ (row&7))*8) + within, chunk = kt*2 + (quad>>1).
    __builtin_amdgcn_s_setprio(1);
#pragma unroll
    for (int dt = 0; dt < 4; dt++) {
      const int row = dt * 16 + l16;
      const half_t* vrow = &vsrc[row * 64 + (quad & 1) * 4];
#pragma unroll
      for (int kt = 0; kt < 4; kt++) {
        half4 bv = *(const half4*)&vrow[((kt * 2 + (quad >> 1)) ^ (l16 & 7)) * 8];
#pragma unroll
        for (int rt = 0; rt < 2; rt++)
          o[rt][dt] = mfma16k16(pa[rt][kt], bv, o[rt][dt]);
      }
    }
    __builtin_amdgcn_s_setprio(0);

    // T14 phase 2: vmcnt wait (first use of rk/rv) lands HERE, after compute.
    if (pf) {
      const int nxt = cur ^ 1;
      *(u32x4*)&Ks[nxt][tid * 8] = rk0;
      *(u32x4*)&Vs[nxt][tid * 8] = rv0;
    }
    __syncthreads();  // lgkm drain + buffer handoff
    cur ^= 1;
  }

  // row sums: lane has partial sum for q = q0+rt*16+l16 over its k subset;
  // reduce across quads (lane bits 4,5), then fetch per-output-row inverse.
  float linv[2][4];
#pragma unroll
  for (int rt = 0; rt < 2; rt++) {
    float s = (vsum[rt][0] + vsum[rt][1]) + (vsum[rt][2] + vsum[rt][3]);
    s += __shfl_xor(s, 16);
    s += __shfl_xor(s, 32);
#pragma unroll
    for (int r = 0; r < 4; r++) linv[rt][r] = 1.f / __shfl(s, quad * 4 + r);
  }
#pragma unroll
  for (int rt = 0; rt < 2; rt++)
#pragma unroll
    for (int dt = 0; dt < 4; dt++)
#pragma unroll
      for (int r = 0; r < 4; r++) {
        int srow = q0 + rt * 16 + quad * 4 + r;
        AO[((size_t)bb * SEQ + srow) * DM + h * DH + dt * 16 + l16] =
            (half_t)(o[rt][dt][r] * linv[rt][r]);
      }
}

// ---------------- output projection ----------------
// Tile 128(m)x64(n), BK=32, grid (16,32) = 512 blocks (2/CU). 4 waves each
// 64x32. 2-phase double-buffered pipeline.

__global__ __launch_bounds__(256)
void out_kernel(const half_t* __restrict__ AO, const half_t* __restrict__ wto,
                const float* __restrict__ bo, float* __restrict__ out) {
  const int tid = threadIdx.x;
  const int wid = tid >> 6, lane = tid & 63;
  const int l16 = lane & 15, quad = lane >> 4;
  const int m0 = blockIdx.y * 128, n0 = blockIdx.x * 64;
  // As0(8K) | As1(8K) | Bs0(4K) | Bs1(4K)
  __shared__ __align__(16) char smem[24576];
  f32x4 acc[4][2] = {};
  const int wrow = (wid >> 1) * 64, wcol = (wid & 1) * 32;

  const int ar0 = tid >> 2,         ab0 = (tid & 3) ^ ((ar0 >> 1) & 3);
  const int ar1 = (tid + 256) >> 2, ab1 = (tid & 3) ^ ((ar1 >> 1) & 3);
  const int swz = (l16 >> 1) & 3;

  // prologue: stage k0=0 into buffer 0
  {
    half_t* As = (half_t*)smem;
    half_t* Bs = (half_t*)(smem + 16384);
    gl2lds16(&AO[(size_t)(m0 + ar0) * DM + ab0 * 8], &As[tid * 8]);
    gl2lds16(&AO[(size_t)(m0 + ar1) * DM + ab1 * 8], &As[(tid + 256) * 8]);
    gl2lds16(&wto[(size_t)(n0 + ar0) * DM + ab0 * 8], &Bs[tid * 8]);
  }
  __syncthreads();

  int cur = 0;
  for (int k0 = 0; k0 < DM; k0 += 32) {
    if (k0 + 32 < DM) {
      half_t* Asn = (half_t*)(smem + (cur ^ 1) * 8192);
      half_t* Bsn = (half_t*)(smem + 16384 + (cur ^ 1) * 4096);
      const int kn = k0 + 32;
      gl2lds16(&AO[(size_t)(m0 + ar0) * DM + kn + ab0 * 8], &Asn[tid * 8]);
      gl2lds16(&AO[(size_t)(m0 + ar1) * DM + kn + ab1 * 8], &Asn[(tid + 256) * 8]);
      gl2lds16(&wto[(size_t)(n0 + ar0) * DM + kn + ab0 * 8], &Bsn[tid * 8]);
    }
    const half_t* Asc = (const half_t*)(smem + cur * 8192);
    const half_t* Bsc = (const half_t*)(smem + 16384 + cur * 4096);
    half8 a[4], b[2];
#pragma unroll
    for (int rt = 0; rt < 4; rt++)
      a[rt] = *(const half8*)&Asc[((wrow + rt * 16 + l16) * 4 + (quad ^ swz)) * 8];
#pragma unroll
    for (int ct = 0; ct < 2; ct++)
      b[ct] = *(const half8*)&Bsc[((wcol + ct * 16 + l16) * 4 + (quad ^ swz)) * 8];
#pragma unroll
    for (int rt = 0; rt < 4; rt++)
#pragma unroll
      for (int ct = 0; ct < 2; ct++)
        acc[rt][ct] = mfma16(a[rt], b[ct], acc[rt][ct]);
    __syncthreads();
    cur ^= 1;
  }
  float bv2[2];
#pragma unroll
  for (int ct = 0; ct < 2; ct++) bv2[ct] = bo[n0 + wcol + ct * 16 + l16];
#pragma unroll
  for (int rt = 0; rt < 4; rt++)
#pragma unroll
    for (int r = 0; r < 4; r++) {
      int m = m0 + wrow + rt * 16 + quad * 4 + r;
#pragma unroll
      for (int ct = 0; ct < 2; ct++)
        out[(size_t)m * DM + n0 + wcol + ct * 16 + l16] = acc[rt][ct][r] + bv2[ct];
    }
}

// ---------------- launch ----------------

extern "C" void kernel_launch(void* const* d_in, const int* in_sizes, int n_in,
                              void* d_out, int out_size, void* d_ws, size_t ws_size,
                              hipStream_t stream) {
  (void)in_sizes; (void)n_in; (void)out_size; (void)ws_size;
  const float* x  = (const float*)d_in[0];
  const float* wq = (const float*)d_in[1];
  const float* bq = (const float*)d_in[2];
  const float* wk = (const float*)d_in[3];
  const float* bk = (const float*)d_in[4];
  const float* wv = (const float*)d_in[5];
  const float* bv = (const float*)d_in[6];
  const float* wo = (const float*)d_in[7];
  const float* bo = (const float*)d_in[8];
  char* ws = (char*)d_ws;
  const size_t MB = 1u << 20;
  // xh and AO share [0,8) MB: xh dead after qkv, AO born after attn.
  half_t* xh  = (half_t*)(ws + 0);
  half_t* AO  = (half_t*)(ws + 0);
  half_t* wtq = (half_t*)(ws + 8 * MB);
  half_t* wtk = (half_t*)(ws + 10 * MB);
  half_t* wtv = (half_t*)(ws + 12 * MB);
  half_t* wto = (half_t*)(ws + 14 * MB);
  float*  st  = (float*)(ws + 16 * MB);
  float*  ctb = (float*)(ws + 16 * MB + 256 * 1024);
  half_t* Qh  = (half_t*)(ws + 17 * MB);
  half_t* Kh  = (half_t*)(ws + 25 * MB);
  half_t* Vt  = (half_t*)(ws + 33 * MB);
  float* out = (float*)d_out;

  prep_kernel<<<8448, 256, 0, stream>>>(x, wq, wk, wv, wo, xh, wtq, wtk, wtv, wto, st, ctb);
  qkv_kernel<<<dim3(8, 32, 3), 256, 0, stream>>>(xh, wtq, wtk, wtv, bq, bk, bv, st, ctb, Qh, Kh, Vt);
  attn_kernel<<<256, 512, 0, stream>>>(Qh, Kh, Vt, AO);
  out_kernel<<<dim3(16, 32), 256, 0, stream>>>(AO, wto, bo, out);
}

// Round 12
// 188.865 us; speedup vs baseline: 1.0343x; 1.0032x over previous
//
#include <hip/hip_runtime.h>

#define DM 1024
#define SEQ 2048
#define NH 16
#define DH 64
#define BATCH 2

typedef _Float16 half_t;
typedef _Float16 half8 __attribute__((ext_vector_type(8)));
typedef _Float16 half4 __attribute__((ext_vector_type(4)));
typedef __fp16 f16x2 __attribute__((ext_vector_type(2)));
typedef unsigned u32x2 __attribute__((ext_vector_type(2)));
typedef unsigned u32x4 __attribute__((ext_vector_type(4)));
typedef float f32x4 __attribute__((ext_vector_type(4)));

__device__ __forceinline__ f32x4 mfma16(half8 a, half8 b, f32x4 c) {
  return __builtin_amdgcn_mfma_f32_16x16x32_f16(a, b, c, 0, 0, 0);
}
// legacy K=16 shape: A[row=l16][k=quad*4+j], B[col=l16][k=quad*4+j],
// D[col=l16][row=quad*4+r] -- A-frag layout matches swapped-QK^T output.
__device__ __forceinline__ f32x4 mfma16k16(half4 a, half4 b, f32x4 c) {
  return __builtin_amdgcn_mfma_f32_16x16x16f16(a, b, c, 0, 0, 0);
}

// async global->LDS, 16B per lane. LDS dest must be wave-uniform base + lane*16.
__device__ __forceinline__ void gl2lds16(const half_t* g, half_t* l) {
  __builtin_amdgcn_global_load_lds((const __attribute__((address_space(1))) void*)g,
                                   (__attribute__((address_space(3))) void*)l, 16, 0, 0);
}

// ---------------- merged prep kernel ----------------
// One dispatch replaces cvt_x / wtrans / ropetab (3 independent jobs).
//   [0,4096)     : x f32 -> f16
//   [4096,8192)  : weight transpose+cvt, 4 matrices x 32x32 tiles
//   [8192,8448)  : rope sin/cos tables

__global__ __launch_bounds__(256)
void prep_kernel(const float* __restrict__ x,
                 const float* __restrict__ w0, const float* __restrict__ w1,
                 const float* __restrict__ w2, const float* __restrict__ w3,
                 half_t* __restrict__ xh,
                 half_t* __restrict__ o0, half_t* __restrict__ o1,
                 half_t* __restrict__ o2, half_t* __restrict__ o3,
                 float* __restrict__ st, float* __restrict__ ct) {
  __shared__ float tile[32][33];
  const int lid = blockIdx.x;
  const int tid = threadIdx.x;
  if (lid < 4096) {
    int i = (lid * 256 + tid) * 4;
    float4 v = *(const float4*)(x + i);
    half4 h = { (half_t)v.x, (half_t)v.y, (half_t)v.z, (half_t)v.w };
    *(half4*)(xh + i) = h;
  } else if (lid < 8192) {
    int l = lid - 4096;
    int z = l >> 10;
    int by = (l >> 5) & 31, bx = l & 31;
    const float* w = (z == 0) ? w0 : (z == 1) ? w1 : (z == 2) ? w2 : w3;
    half_t* o = (z == 0) ? o0 : (z == 1) ? o1 : (z == 2) ? o2 : o3;
    int tx = tid & 31, ty0 = tid >> 5;
    int bxx = bx * 32, byy = by * 32;
#pragma unroll
    for (int i = 0; i < 4; i++) {
      int ty = ty0 + i * 8;
      tile[ty][tx] = w[(size_t)(byy + ty) * DM + bxx + tx];
    }
    __syncthreads();
#pragma unroll
    for (int i = 0; i < 4; i++) {
      int ty = ty0 + i * 8;
      o[(size_t)(bxx + ty) * DM + byy + tx] = (half_t)tile[tx][ty];
    }
  } else {
    int idx = (lid - 8192) * 256 + tid;  // 65536 = 2048*32
    int s = idx >> 5, i = idx & 31;
    float freq = exp2f(-(float)i * (13.287712379549449f / 32.0f));
    float ang = (float)s * freq;
    st[idx] = sinf(ang);
    ct[idx] = cosf(ang);
  }
}

// ---------------- QKV projection GEMM + bias + RoPE ----------------
// grid: (8, 32, 3) blocks of 256. Tile 128x128, BK=32, 4 waves each 64x64.
// 2-phase double-buffered pipeline; one barrier per K-step.
// Q pre-scaled by (1/sqrt(DH))*log2(e). V written TRANSPOSED [bh][d][s].

__global__ __launch_bounds__(256)
void qkv_kernel(const half_t* __restrict__ xh,
                const half_t* __restrict__ wtq, const half_t* __restrict__ wtk,
                const half_t* __restrict__ wtv,
                const float* __restrict__ bq, const float* __restrict__ bk,
                const float* __restrict__ bv,
                const float* __restrict__ st, const float* __restrict__ ctab,
                half_t* __restrict__ Qh, half_t* __restrict__ Kh, half_t* __restrict__ Vt) {
  const int tid = threadIdx.x;
  const int wid = tid >> 6, lane = tid & 63;
  const int l16 = lane & 15, quad = lane >> 4;
  const int m0 = blockIdx.y * 128, n0 = blockIdx.x * 128;
  const int g = blockIdx.z;
  const half_t* wt = (g == 0) ? wtq : (g == 1) ? wtk : wtv;
  const float* bias = (g == 0) ? bq : (g == 1) ? bk : bv;
  // As0 | As1 | Bs0 | Bs1 (8KB each); vtile(4x8KB) overlays after the K-loop
  __shared__ __align__(16) char smem[32768];
  f32x4 acc[4][4] = {};
  const int wrow = (wid >> 1) * 64, wcol = (wid & 1) * 64;

  const int ar0 = tid >> 2,          ab0 = (tid & 3) ^ ((ar0 >> 1) & 3);
  const int ar1 = (tid + 256) >> 2,  ab1 = (tid & 3) ^ ((ar1 >> 1) & 3);
  const int swz = (l16 >> 1) & 3;

  // prologue: stage k0=0 into buffer 0
  {
    half_t* As = (half_t*)smem;
    half_t* Bs = (half_t*)(smem + 16384);
    gl2lds16(&xh[(size_t)(m0 + ar0) * DM + ab0 * 8], &As[tid * 8]);
    gl2lds16(&xh[(size_t)(m0 + ar1) * DM + ab1 * 8], &As[(tid + 256) * 8]);
    gl2lds16(&wt[(size_t)(n0 + ar0) * DM + ab0 * 8], &Bs[tid * 8]);
    gl2lds16(&wt[(size_t)(n0 + ar1) * DM + ab1 * 8], &Bs[(tid + 256) * 8]);
  }
  __syncthreads();

  int cur = 0;
  for (int k0 = 0; k0 < DM; k0 += 32) {
    // phase 1: issue next tile's staging into buf^1 (in flight across compute)
    if (k0 + 32 < DM) {
      half_t* Asn = (half_t*)(smem + (cur ^ 1) * 8192);
      half_t* Bsn = (half_t*)(smem + 16384 + (cur ^ 1) * 8192);
      const int kn = k0 + 32;
      gl2lds16(&xh[(size_t)(m0 + ar0) * DM + kn + ab0 * 8], &Asn[tid * 8]);
      gl2lds16(&xh[(size_t)(m0 + ar1) * DM + kn + ab1 * 8], &Asn[(tid + 256) * 8]);
      gl2lds16(&wt[(size_t)(n0 + ar0) * DM + kn + ab0 * 8], &Bsn[tid * 8]);
      gl2lds16(&wt[(size_t)(n0 + ar1) * DM + kn + ab1 * 8], &Bsn[(tid + 256) * 8]);
    }
    // phase 2: compute current tile
    const half_t* Asc = (const half_t*)(smem + cur * 8192);
    const half_t* Bsc = (const half_t*)(smem + 16384 + cur * 8192);
    half8 a[4], b[4];
#pragma unroll
    for (int rt = 0; rt < 4; rt++)
      a[rt] = *(const half8*)&Asc[((wrow + rt * 16 + l16) * 4 + (quad ^ swz)) * 8];
#pragma unroll
    for (int ct = 0; ct < 4; ct++)
      b[ct] = *(const half8*)&Bsc[((wcol + ct * 16 + l16) * 4 + (quad ^ swz)) * 8];
#pragma unroll
    for (int rt = 0; rt < 4; rt++)
#pragma unroll
      for (int ct = 0; ct < 4; ct++)
        acc[rt][ct] = mfma16(a[rt], b[ct], acc[rt][ct]);
    __syncthreads();  // drains next-tile vmcnt (overlapped) + protects cur
    cur ^= 1;
  }

  // epilogue (loop ended with a barrier -> smem reusable as vtile)
  const int h = (n0 + wcol) >> 6;  // wave col-span (64) == one head
  const float qscale = 0.125f * 1.44269504089f;
  float bv4[4];
#pragma unroll
  for (int ct = 0; ct < 4; ct++) bv4[ct] = bias[n0 + wcol + ct * 16 + l16];

  if (g == 2) {
    // V path: per-wave transpose via LDS, 16B-unit XOR swizzle:
    //   vt[row*64 + ((col>>3 ^ (row&7))*8) + (col&7)]
    half_t* vt = (half_t*)(smem + wid * 8192);
#pragma unroll
    for (int rt = 0; rt < 4; rt++)
#pragma unroll
      for (int ct = 0; ct < 4; ct++) {
        half4 hv;
#pragma unroll
        for (int r = 0; r < 4; r++) hv[r] = (half_t)(acc[rt][ct][r] + bv4[ct]);
        int row = ct * 16 + l16;                  // d
        int colu = rt * 2 + (quad >> 1);          // s-chunk (8 halves)
        *(half4*)&vt[row * 64 + ((colu ^ (row & 7)) * 8) + (quad & 1) * 4] = hv;
      }
    const int sb = m0 + wrow;  // 64 consecutive rows, within one batch
    const int bb = sb >> 11, s0 = sb & 2047;
    half_t* dstv = Vt + (size_t)(bb * NH + h) * DH * SEQ;
#pragma unroll
    for (int i = 0; i < 8; i++) {
      int d = i * 8 + (lane >> 3), c = lane & 7;
      half8 v = *(const half8*)&vt[d * 64 + ((c ^ (d & 7)) * 8)];
      *(half8*)&dstv[(size_t)d * SEQ + s0 + c * 8] = v;
    }
  } else {
    // Q/K path: bias + RoPE (+ qscale for Q); coalesced [bh][s][d] stores
    half_t* dst = (g == 0) ? Qh : Kh;
#pragma unroll
    for (int rt = 0; rt < 4; rt++) {
#pragma unroll
      for (int r = 0; r < 4; r++) {
        int m = m0 + wrow + rt * 16 + quad * 4 + r;
        int bb = m >> 11, s = m & 2047;
        float v0 = acc[rt][0][r] + bv4[0];  // d = l16
        float v1 = acc[rt][1][r] + bv4[1];  // d = 16+l16
        float v2 = acc[rt][2][r] + bv4[2];  // d = 32+l16
        float v3 = acc[rt][3][r] + bv4[3];  // d = 48+l16
        float sn0 = st[s * 32 + l16], cs0 = ctab[s * 32 + l16];
        float sn1 = st[s * 32 + 16 + l16], cs1 = ctab[s * 32 + 16 + l16];
        float o0 = v0 * cs0 - v2 * sn0;
        float o1 = v1 * cs1 - v3 * sn1;
        float o2 = v2 * cs0 + v0 * sn0;
        float o3 = v3 * cs1 + v1 * sn1;
        if (g == 0) { o0 *= qscale; o1 *= qscale; o2 *= qscale; o3 *= qscale; }
        size_t base = ((size_t)(bb * NH + h) * SEQ + s) * DH;
        dst[base + l16]      = (half_t)o0;
        dst[base + 16 + l16] = (half_t)o1;
        dst[base + 32 + l16] = (half_t)o2;
        dst[base + 48 + l16] = (half_t)o3;
      }
    }
  }
}

// ---------------- flash attention (v5 -- best measured, 48.6-49.0 us) --------
// 8-wave blocks (512 thr), 256 q-rows/block, K/V staged once per CU per
// 64-k tile (one K slot + one V slot per thread), XCD affinity, T14
// reg-staging, swapped QK^T, P-in-register PV via K=16 MFMA, s_setprio.
// Kept verbatim; v6/v7/v8/v9 variants all measured equal or worse.

__global__ __launch_bounds__(512)
void attn_kernel(const half_t* __restrict__ Qh, const half_t* __restrict__ Kh,
                 const half_t* __restrict__ Vt, half_t* __restrict__ AO) {
  const int tid = threadIdx.x;
  const int wid = tid >> 6, lane = tid & 63;
  const int l16 = lane & 15, quad = lane >> 4;
  const int lid = blockIdx.x;              // 256 blocks
  const int bh = lid & 31, qt = lid >> 5;  // same-bh -> same XCD
  const int bb = bh >> 4, h = bh & 15;
  const int q0 = qt * 256 + wid * 32;
  const half_t* Q = Qh + (size_t)bh * SEQ * DH;
  const half_t* K = Kh + (size_t)bh * SEQ * DH;
  const half_t* V = Vt + (size_t)bh * DH * SEQ;
  __shared__ __align__(16) half_t Ks[2][64 * 64];
  __shared__ __align__(16) half_t Vs[2][64 * 64];

  // staging slot: 512 threads x 16B = one 64x64 tile; XOR chunk swizzle
  const int r0 = tid >> 3, c0 = (tid & 7) ^ (r0 & 7);
  // swizzled ds_read chunk offsets (halves) for logical d-chunks quad, quad+4
  const int sw0 = ((quad ^ (l16 & 7)) * 8);
  const int sw1 = (((quad + 4) ^ (l16 & 7)) * 8);

  const half_t* gK0 = &K[(size_t)r0 * DH + c0 * 8];
  const half_t* gV0 = &V[(size_t)r0 * SEQ + c0 * 8];

  // Q fragments: lane holds Q[q0+rt*16+l16][quad*8+j] (+32 for B-chunk hi)
  half8 aqA[2], aqB[2];
#pragma unroll
  for (int rt = 0; rt < 2; rt++) {
    aqA[rt] = *(const half8*)&Q[(size_t)(q0 + rt * 16 + l16) * DH + quad * 8];
    aqB[rt] = *(const half8*)&Q[(size_t)(q0 + rt * 16 + l16) * DH + 32 + quad * 8];
  }

  f32x4 o[2][4] = {};
  f32x4 vsum[2] = {};
  const f32x4 cinit = {-12.f, -12.f, -12.f, -12.f};

  // prologue: stage tile 0 into buffer 0 (async; barrier drains vmcnt)
  gl2lds16(gK0, &Ks[0][tid * 8]);
  gl2lds16(gV0, &Vs[0][tid * 8]);
  __syncthreads();

  int cur = 0;
  for (int kb0 = 0; kb0 < SEQ; kb0 += 64) {
    const bool pf = (kb0 + 64 < SEQ);
    // T14 phase 1: issue next tile's global loads into registers NOW.
    u32x4 rk0, rv0;
    if (pf) {
      const int kb = kb0 + 64;
      rk0 = *(const u32x4*)(gK0 + (size_t)kb * DH);
      rv0 = *(const u32x4*)(gV0 + kb);
    }
    const half_t* ksrc = Ks[cur];
    const half_t* vsrc = Vs[cur];

    // QK^T swapped: A = K rows, B = Q rows. z[rt][kt][r] =
    // S[q = q0+rt*16+l16][k = kb0+kt*16+quad*4+r] - 12
    f32x4 z[2][4];
    __builtin_amdgcn_s_setprio(1);
#pragma unroll
    for (int kt = 0; kt < 4; kt++) {
      const half_t* krow = &ksrc[(kt * 16 + l16) * 64];
      half8 b0 = *(const half8*)&krow[sw0];
      half8 b1 = *(const half8*)&krow[sw1];
#pragma unroll
      for (int rt = 0; rt < 2; rt++) {
        f32x4 zz = cinit;
        zz = mfma16(b0, aqA[rt], zz);
        zz = mfma16(b1, aqB[rt], zz);
        z[rt][kt] = zz;
      }
    }
    __builtin_amdgcn_s_setprio(0);

    // softmax: exp2, f32 row-sum, packed f16 convert -> pa[rt][kt] is the
    // READY A-fragment for the K=16 PV MFMA (k = kt*16 + quad*4 + j).
    half4 pa[2][4];
#pragma unroll
    for (int rt = 0; rt < 2; rt++)
#pragma unroll
      for (int kt = 0; kt < 4; kt++) {
        f32x4 p;
#pragma unroll
        for (int r = 0; r < 4; r++) p[r] = __builtin_amdgcn_exp2f(z[rt][kt][r]);
        vsum[rt] += p;
        f16x2 lo = __builtin_amdgcn_cvt_pkrtz(p[0], p[1]);
        f16x2 hi = __builtin_amdgcn_cvt_pkrtz(p[2], p[3]);
        u32x2 w = { __builtin_bit_cast(unsigned, lo), __builtin_bit_cast(unsigned, hi) };
        pa[rt][kt] = __builtin_bit_cast(half4, w);
      }

    // PV: o[q][d] += P * V. B-frag = V[k=kt*16+quad*4+j][d=dt*16+l16], a
    // half4 from swizzled Vs (V^T rows d): phys = row*64 +
    // ((chunk ^ (row&7))*8) + within, chunk = kt*2 + (quad>>1).
    __builtin_amdgcn_s_setprio(1);
#pragma unroll
    for (int dt = 0; dt < 4; dt++) {
      const int row = dt * 16 + l16;
      const half_t* vrow = &vsrc[row * 64 + (quad & 1) * 4];
#pragma unroll
      for (int kt = 0; kt < 4; kt++) {
        half4 bv = *(const half4*)&vrow[((kt * 2 + (quad >> 1)) ^ (l16 & 7)) * 8];
#pragma unroll
        for (int rt = 0; rt < 2; rt++)
          o[rt][dt] = mfma16k16(pa[rt][kt], bv, o[rt][dt]);
      }
    }
    __builtin_amdgcn_s_setprio(0);

    // T14 phase 2: vmcnt wait (first use of rk/rv) lands HERE, after compute.
    if (pf) {
      const int nxt = cur ^ 1;
      *(u32x4*)&Ks[nxt][tid * 8] = rk0;
      *(u32x4*)&Vs[nxt][tid * 8] = rv0;
    }
    __syncthreads();  // lgkm drain + buffer handoff
    cur ^= 1;
  }

  // row sums: lane has partial sum for q = q0+rt*16+l16 over its k subset;
  // reduce across quads (lane bits 4,5), then fetch per-output-row inverse.
  float linv[2][4];
#pragma unroll
  for (int rt = 0; rt < 2; rt++) {
    float s = (vsum[rt][0] + vsum[rt][1]) + (vsum[rt][2] + vsum[rt][3]);
    s += __shfl_xor(s, 16);
    s += __shfl_xor(s, 32);
#pragma unroll
    for (int r = 0; r < 4; r++) linv[rt][r] = 1.f / __shfl(s, quad * 4 + r);
  }
#pragma unroll
  for (int rt = 0; rt < 2; rt++)
#pragma unroll
    for (int dt = 0; dt < 4; dt++)
#pragma unroll
      for (int r = 0; r < 4; r++) {
        int srow = q0 + rt * 16 + quad * 4 + r;
        AO[((size_t)bb * SEQ + srow) * DM + h * DH + dt * 16 + l16] =
            (half_t)(o[rt][dt][r] * linv[rt][r]);
      }
}

// ---------------- output projection (v2: 128x128 tile) ----------------
// Clones qkv's proven K-loop: tile 128(m)x128(n), BK=32, grid (8,32) =
// 256 blocks (1/CU), 4 waves each 64x64, 16 MFMA per K-step against 16KB
// staging (was 128x64: 8 MFMA / 12KB, 512 blocks -> ~1.5KB staging/MFMA).
// f32 epilogue with bias.

__global__ __launch_bounds__(256)
void out_kernel(const half_t* __restrict__ AO, const half_t* __restrict__ wto,
                const float* __restrict__ bo, float* __restrict__ out) {
  const int tid = threadIdx.x;
  const int wid = tid >> 6, lane = tid & 63;
  const int l16 = lane & 15, quad = lane >> 4;
  const int m0 = blockIdx.y * 128, n0 = blockIdx.x * 128;
  // As0 | As1 | Bs0 | Bs1 (8KB each)
  __shared__ __align__(16) char smem[32768];
  f32x4 acc[4][4] = {};
  const int wrow = (wid >> 1) * 64, wcol = (wid & 1) * 64;

  const int ar0 = tid >> 2,          ab0 = (tid & 3) ^ ((ar0 >> 1) & 3);
  const int ar1 = (tid + 256) >> 2,  ab1 = (tid & 3) ^ ((ar1 >> 1) & 3);
  const int swz = (l16 >> 1) & 3;

  // prologue: stage k0=0 into buffer 0
  {
    half_t* As = (half_t*)smem;
    half_t* Bs = (half_t*)(smem + 16384);
    gl2lds16(&AO[(size_t)(m0 + ar0) * DM + ab0 * 8], &As[tid * 8]);
    gl2lds16(&AO[(size_t)(m0 + ar1) * DM + ab1 * 8], &As[(tid + 256) * 8]);
    gl2lds16(&wto[(size_t)(n0 + ar0) * DM + ab0 * 8], &Bs[tid * 8]);
    gl2lds16(&wto[(size_t)(n0 + ar1) * DM + ab1 * 8], &Bs[(tid + 256) * 8]);
  }
  __syncthreads();

  int cur = 0;
  for (int k0 = 0; k0 < DM; k0 += 32) {
    if (k0 + 32 < DM) {
      half_t* Asn = (half_t*)(smem + (cur ^ 1) * 8192);
      half_t* Bsn = (half_t*)(smem + 16384 + (cur ^ 1) * 8192);
      const int kn = k0 + 32;
      gl2lds16(&AO[(size_t)(m0 + ar0) * DM + kn + ab0 * 8], &Asn[tid * 8]);
      gl2lds16(&AO[(size_t)(m0 + ar1) * DM + kn + ab1 * 8], &Asn[(tid + 256) * 8]);
      gl2lds16(&wto[(size_t)(n0 + ar0) * DM + kn + ab0 * 8], &Bsn[tid * 8]);
      gl2lds16(&wto[(size_t)(n0 + ar1) * DM + kn + ab1 * 8], &Bsn[(tid + 256) * 8]);
    }
    const half_t* Asc = (const half_t*)(smem + cur * 8192);
    const half_t* Bsc = (const half_t*)(smem + 16384 + cur * 8192);
    half8 a[4], b[4];
#pragma unroll
    for (int rt = 0; rt < 4; rt++)
      a[rt] = *(const half8*)&Asc[((wrow + rt * 16 + l16) * 4 + (quad ^ swz)) * 8];
#pragma unroll
    for (int ct = 0; ct < 4; ct++)
      b[ct] = *(const half8*)&Bsc[((wcol + ct * 16 + l16) * 4 + (quad ^ swz)) * 8];
#pragma unroll
    for (int rt = 0; rt < 4; rt++)
#pragma unroll
      for (int ct = 0; ct < 4; ct++)
        acc[rt][ct] = mfma16(a[rt], b[ct], acc[rt][ct]);
    __syncthreads();
    cur ^= 1;
  }
  float bv4[4];
#pragma unroll
  for (int ct = 0; ct < 4; ct++) bv4[ct] = bo[n0 + wcol + ct * 16 + l16];
#pragma unroll
  for (int rt = 0; rt < 4; rt++)
#pragma unroll
    for (int r = 0; r < 4; r++) {
      int m = m0 + wrow + rt * 16 + quad * 4 + r;
#pragma unroll
      for (int ct = 0; ct < 4; ct++)
        out[(size_t)m * DM + n0 + wcol + ct * 16 + l16] = acc[rt][ct][r] + bv4[ct];
    }
}

// ---------------- launch ----------------

extern "C" void kernel_launch(void* const* d_in, const int* in_sizes, int n_in,
                              void* d_out, int out_size, void* d_ws, size_t ws_size,
                              hipStream_t stream) {
  (void)in_sizes; (void)n_in; (void)out_size; (void)ws_size;
  const float* x  = (const float*)d_in[0];
  const float* wq = (const float*)d_in[1];
  const float* bq = (const float*)d_in[2];
  const float* wk = (const float*)d_in[3];
  const float* bk = (const float*)d_in[4];
  const float* wv = (const float*)d_in[5];
  const float* bv = (const float*)d_in[6];
  const float* wo = (const float*)d_in[7];
  const float* bo = (const float*)d_in[8];
  char* ws = (char*)d_ws;
  const size_t MB = 1u << 20;
  // xh and AO share [0,8) MB: xh dead after qkv, AO born after attn.
  half_t* xh  = (half_t*)(ws + 0);
  half_t* AO  = (half_t*)(ws + 0);
  half_t* wtq = (half_t*)(ws + 8 * MB);
  half_t* wtk = (half_t*)(ws + 10 * MB);
  half_t* wtv = (half_t*)(ws + 12 * MB);
  half_t* wto = (half_t*)(ws + 14 * MB);
  float*  st  = (float*)(ws + 16 * MB);
  float*  ctb = (float*)(ws + 16 * MB + 256 * 1024);
  half_t* Qh  = (half_t*)(ws + 17 * MB);
  half_t* Kh  = (half_t*)(ws + 25 * MB);
  half_t* Vt  = (half_t*)(ws + 33 * MB);
  float* out = (float*)d_out;

  prep_kernel<<<8448, 256, 0, stream>>>(x, wq, wk, wv, wo, xh, wtq, wtk, wtv, wto, st, ctb);
  qkv_kernel<<<dim3(8, 32, 3), 256, 0, stream>>>(xh, wtq, wtk, wtv, bq, bk, bv, st, ctb, Qh, Kh, Vt);
  attn_kernel<<<256, 512, 0, stream>>>(Qh, Kh, Vt, AO);
  out_kernel<<<dim3(8, 32), 256, 0, stream>>>(AO, wto, bo, out);
}

// Round 13
// 186.445 us; speedup vs baseline: 1.0477x; 1.0130x over previous
//
#include <hip/hip_runtime.h>

#define DM 1024
#define SEQ 2048
#define NH 16
#define DH 64
#define BATCH 2

typedef _Float16 half_t;
typedef _Float16 half8 __attribute__((ext_vector_type(8)));
typedef _Float16 half4 __attribute__((ext_vector_type(4)));
typedef __fp16 f16x2 __attribute__((ext_vector_type(2)));
typedef unsigned u32x2 __attribute__((ext_vector_type(2)));
typedef unsigned u32x4 __attribute__((ext_vector_type(4)));
typedef float f32x4 __attribute__((ext_vector_type(4)));

__device__ __forceinline__ f32x4 mfma16(half8 a, half8 b, f32x4 c) {
  return __builtin_amdgcn_mfma_f32_16x16x32_f16(a, b, c, 0, 0, 0);
}
// legacy K=16 shape: A[row=l16][k=quad*4+j], B[col=l16][k=quad*4+j],
// D[col=l16][row=quad*4+r] -- A-frag layout matches swapped-QK^T output.
__device__ __forceinline__ f32x4 mfma16k16(half4 a, half4 b, f32x4 c) {
  return __builtin_amdgcn_mfma_f32_16x16x16f16(a, b, c, 0, 0, 0);
}

// async global->LDS, 16B per lane. LDS dest must be wave-uniform base + lane*16.
__device__ __forceinline__ void gl2lds16(const half_t* g, half_t* l) {
  __builtin_amdgcn_global_load_lds((const __attribute__((address_space(1))) void*)g,
                                   (__attribute__((address_space(3))) void*)l, 16, 0, 0);
}

// ---------------- merged prep kernel ----------------
// One dispatch replaces cvt_x / wtrans / ropetab (3 independent jobs).
//   [0,4096)     : x f32 -> f16
//   [4096,8192)  : weight transpose+cvt, 4 matrices x 32x32 tiles
//   [8192,8448)  : rope sin/cos tables

__global__ __launch_bounds__(256)
void prep_kernel(const float* __restrict__ x,
                 const float* __restrict__ w0, const float* __restrict__ w1,
                 const float* __restrict__ w2, const float* __restrict__ w3,
                 half_t* __restrict__ xh,
                 half_t* __restrict__ o0, half_t* __restrict__ o1,
                 half_t* __restrict__ o2, half_t* __restrict__ o3,
                 float* __restrict__ st, float* __restrict__ ct) {
  __shared__ float tile[32][33];
  const int lid = blockIdx.x;
  const int tid = threadIdx.x;
  if (lid < 4096) {
    int i = (lid * 256 + tid) * 4;
    float4 v = *(const float4*)(x + i);
    half4 h = { (half_t)v.x, (half_t)v.y, (half_t)v.z, (half_t)v.w };
    *(half4*)(xh + i) = h;
  } else if (lid < 8192) {
    int l = lid - 4096;
    int z = l >> 10;
    int by = (l >> 5) & 31, bx = l & 31;
    const float* w = (z == 0) ? w0 : (z == 1) ? w1 : (z == 2) ? w2 : w3;
    half_t* o = (z == 0) ? o0 : (z == 1) ? o1 : (z == 2) ? o2 : o3;
    int tx = tid & 31, ty0 = tid >> 5;
    int bxx = bx * 32, byy = by * 32;
#pragma unroll
    for (int i = 0; i < 4; i++) {
      int ty = ty0 + i * 8;
      tile[ty][tx] = w[(size_t)(byy + ty) * DM + bxx + tx];
    }
    __syncthreads();
#pragma unroll
    for (int i = 0; i < 4; i++) {
      int ty = ty0 + i * 8;
      o[(size_t)(bxx + ty) * DM + byy + tx] = (half_t)tile[tx][ty];
    }
  } else {
    int idx = (lid - 8192) * 256 + tid;  // 65536 = 2048*32
    int s = idx >> 5, i = idx & 31;
    float freq = exp2f(-(float)i * (13.287712379549449f / 32.0f));
    float ang = (float)s * freq;
    st[idx] = sinf(ang);
    ct[idx] = cosf(ang);
  }
}

// ---------------- QKV projection GEMM + bias + RoPE ----------------
// grid: (8, 32, 3) blocks of 256. Tile 128x128, BK=32, 4 waves each 64x64.
// 2-phase double-buffered pipeline; one barrier per K-step.
// Q pre-scaled by (1/sqrt(DH))*log2(e). V written TRANSPOSED [bh][d][s].

__global__ __launch_bounds__(256)
void qkv_kernel(const half_t* __restrict__ xh,
                const half_t* __restrict__ wtq, const half_t* __restrict__ wtk,
                const half_t* __restrict__ wtv,
                const float* __restrict__ bq, const float* __restrict__ bk,
                const float* __restrict__ bv,
                const float* __restrict__ st, const float* __restrict__ ctab,
                half_t* __restrict__ Qh, half_t* __restrict__ Kh, half_t* __restrict__ Vt) {
  const int tid = threadIdx.x;
  const int wid = tid >> 6, lane = tid & 63;
  const int l16 = lane & 15, quad = lane >> 4;
  const int m0 = blockIdx.y * 128, n0 = blockIdx.x * 128;
  const int g = blockIdx.z;
  const half_t* wt = (g == 0) ? wtq : (g == 1) ? wtk : wtv;
  const float* bias = (g == 0) ? bq : (g == 1) ? bk : bv;
  // As0 | As1 | Bs0 | Bs1 (8KB each); vtile(4x8KB) overlays after the K-loop
  __shared__ __align__(16) char smem[32768];
  f32x4 acc[4][4] = {};
  const int wrow = (wid >> 1) * 64, wcol = (wid & 1) * 64;

  const int ar0 = tid >> 2,          ab0 = (tid & 3) ^ ((ar0 >> 1) & 3);
  const int ar1 = (tid + 256) >> 2,  ab1 = (tid & 3) ^ ((ar1 >> 1) & 3);
  const int swz = (l16 >> 1) & 3;

  // prologue: stage k0=0 into buffer 0
  {
    half_t* As = (half_t*)smem;
    half_t* Bs = (half_t*)(smem + 16384);
    gl2lds16(&xh[(size_t)(m0 + ar0) * DM + ab0 * 8], &As[tid * 8]);
    gl2lds16(&xh[(size_t)(m0 + ar1) * DM + ab1 * 8], &As[(tid + 256) * 8]);
    gl2lds16(&wt[(size_t)(n0 + ar0) * DM + ab0 * 8], &Bs[tid * 8]);
    gl2lds16(&wt[(size_t)(n0 + ar1) * DM + ab1 * 8], &Bs[(tid + 256) * 8]);
  }
  __syncthreads();

  int cur = 0;
  for (int k0 = 0; k0 < DM; k0 += 32) {
    // phase 1: issue next tile's staging into buf^1 (in flight across compute)
    if (k0 + 32 < DM) {
      half_t* Asn = (half_t*)(smem + (cur ^ 1) * 8192);
      half_t* Bsn = (half_t*)(smem + 16384 + (cur ^ 1) * 8192);
      const int kn = k0 + 32;
      gl2lds16(&xh[(size_t)(m0 + ar0) * DM + kn + ab0 * 8], &Asn[tid * 8]);
      gl2lds16(&xh[(size_t)(m0 + ar1) * DM + kn + ab1 * 8], &Asn[(tid + 256) * 8]);
      gl2lds16(&wt[(size_t)(n0 + ar0) * DM + kn + ab0 * 8], &Bsn[tid * 8]);
      gl2lds16(&wt[(size_t)(n0 + ar1) * DM + kn + ab1 * 8], &Bsn[(tid + 256) * 8]);
    }
    // phase 2: compute current tile
    const half_t* Asc = (const half_t*)(smem + cur * 8192);
    const half_t* Bsc = (const half_t*)(smem + 16384 + cur * 8192);
    half8 a[4], b[4];
#pragma unroll
    for (int rt = 0; rt < 4; rt++)
      a[rt] = *(const half8*)&Asc[((wrow + rt * 16 + l16) * 4 + (quad ^ swz)) * 8];
#pragma unroll
    for (int ct = 0; ct < 4; ct++)
      b[ct] = *(const half8*)&Bsc[((wcol + ct * 16 + l16) * 4 + (quad ^ swz)) * 8];
#pragma unroll
    for (int rt = 0; rt < 4; rt++)
#pragma unroll
      for (int ct = 0; ct < 4; ct++)
        acc[rt][ct] = mfma16(a[rt], b[ct], acc[rt][ct]);
    __syncthreads();  // drains next-tile vmcnt (overlapped) + protects cur
    cur ^= 1;
  }

  // epilogue (loop ended with a barrier -> smem reusable as vtile)
  const int h = (n0 + wcol) >> 6;  // wave col-span (64) == one head
  const float qscale = 0.125f * 1.44269504089f;
  float bv4[4];
#pragma unroll
  for (int ct = 0; ct < 4; ct++) bv4[ct] = bias[n0 + wcol + ct * 16 + l16];

  if (g == 2) {
    // V path: per-wave transpose via LDS, 16B-unit XOR swizzle:
    //   vt[row*64 + ((col>>3 ^ (row&7))*8) + (col&7)]
    half_t* vt = (half_t*)(smem + wid * 8192);
#pragma unroll
    for (int rt = 0; rt < 4; rt++)
#pragma unroll
      for (int ct = 0; ct < 4; ct++) {
        half4 hv;
#pragma unroll
        for (int r = 0; r < 4; r++) hv[r] = (half_t)(acc[rt][ct][r] + bv4[ct]);
        int row = ct * 16 + l16;                  // d
        int colu = rt * 2 + (quad >> 1);          // s-chunk (8 halves)
        *(half4*)&vt[row * 64 + ((colu ^ (row & 7)) * 8) + (quad & 1) * 4] = hv;
      }
    const int sb = m0 + wrow;  // 64 consecutive rows, within one batch
    const int bb = sb >> 11, s0 = sb & 2047;
    half_t* dstv = Vt + (size_t)(bb * NH + h) * DH * SEQ;
#pragma unroll
    for (int i = 0; i < 8; i++) {
      int d = i * 8 + (lane >> 3), c = lane & 7;
      half8 v = *(const half8*)&vt[d * 64 + ((c ^ (d & 7)) * 8)];
      *(half8*)&dstv[(size_t)d * SEQ + s0 + c * 8] = v;
    }
  } else {
    // Q/K path: bias + RoPE (+ qscale for Q); coalesced [bh][s][d] stores
    half_t* dst = (g == 0) ? Qh : Kh;
#pragma unroll
    for (int rt = 0; rt < 4; rt++) {
#pragma unroll
      for (int r = 0; r < 4; r++) {
        int m = m0 + wrow + rt * 16 + quad * 4 + r;
        int bb = m >> 11, s = m & 2047;
        float v0 = acc[rt][0][r] + bv4[0];  // d = l16
        float v1 = acc[rt][1][r] + bv4[1];  // d = 16+l16
        float v2 = acc[rt][2][r] + bv4[2];  // d = 32+l16
        float v3 = acc[rt][3][r] + bv4[3];  // d = 48+l16
        float sn0 = st[s * 32 + l16], cs0 = ctab[s * 32 + l16];
        float sn1 = st[s * 32 + 16 + l16], cs1 = ctab[s * 32 + 16 + l16];
        float o0 = v0 * cs0 - v2 * sn0;
        float o1 = v1 * cs1 - v3 * sn1;
        float o2 = v2 * cs0 + v0 * sn0;
        float o3 = v3 * cs1 + v1 * sn1;
        if (g == 0) { o0 *= qscale; o1 *= qscale; o2 *= qscale; o3 *= qscale; }
        size_t base = ((size_t)(bb * NH + h) * SEQ + s) * DH;
        dst[base + l16]      = (half_t)o0;
        dst[base + 16 + l16] = (half_t)o1;
        dst[base + 32 + l16] = (half_t)o2;
        dst[base + 48 + l16] = (half_t)o3;
      }
    }
  }
}

// ---------------- flash attention (v5 -- best measured, 48.6-49.0 us) --------
// 8-wave blocks (512 thr), 256 q-rows/block, K/V staged once per CU per
// 64-k tile (one K slot + one V slot per thread), XCD affinity, T14
// reg-staging, swapped QK^T, P-in-register PV via K=16 MFMA, s_setprio.
// Kept verbatim; v6/v7/v8/v9 variants all measured equal or worse.

__global__ __launch_bounds__(512)
void attn_kernel(const half_t* __restrict__ Qh, const half_t* __restrict__ Kh,
                 const half_t* __restrict__ Vt, half_t* __restrict__ AO) {
  const int tid = threadIdx.x;
  const int wid = tid >> 6, lane = tid & 63;
  const int l16 = lane & 15, quad = lane >> 4;
  const int lid = blockIdx.x;              // 256 blocks
  const int bh = lid & 31, qt = lid >> 5;  // same-bh -> same XCD
  const int bb = bh >> 4, h = bh & 15;
  const int q0 = qt * 256 + wid * 32;
  const half_t* Q = Qh + (size_t)bh * SEQ * DH;
  const half_t* K = Kh + (size_t)bh * SEQ * DH;
  const half_t* V = Vt + (size_t)bh * DH * SEQ;
  __shared__ __align__(16) half_t Ks[2][64 * 64];
  __shared__ __align__(16) half_t Vs[2][64 * 64];

  // staging slot: 512 threads x 16B = one 64x64 tile; XOR chunk swizzle
  const int r0 = tid >> 3, c0 = (tid & 7) ^ (r0 & 7);
  // swizzled ds_read chunk offsets (halves) for logical d-chunks quad, quad+4
  const int sw0 = ((quad ^ (l16 & 7)) * 8);
  const int sw1 = (((quad + 4) ^ (l16 & 7)) * 8);

  const half_t* gK0 = &K[(size_t)r0 * DH + c0 * 8];
  const half_t* gV0 = &V[(size_t)r0 * SEQ + c0 * 8];

  // Q fragments: lane holds Q[q0+rt*16+l16][quad*8+j] (+32 for B-chunk hi)
  half8 aqA[2], aqB[2];
#pragma unroll
  for (int rt = 0; rt < 2; rt++) {
    aqA[rt] = *(const half8*)&Q[(size_t)(q0 + rt * 16 + l16) * DH + quad * 8];
    aqB[rt] = *(const half8*)&Q[(size_t)(q0 + rt * 16 + l16) * DH + 32 + quad * 8];
  }

  f32x4 o[2][4] = {};
  f32x4 vsum[2] = {};
  const f32x4 cinit = {-12.f, -12.f, -12.f, -12.f};

  // prologue: stage tile 0 into buffer 0 (async; barrier drains vmcnt)
  gl2lds16(gK0, &Ks[0][tid * 8]);
  gl2lds16(gV0, &Vs[0][tid * 8]);
  __syncthreads();

  int cur = 0;
  for (int kb0 = 0; kb0 < SEQ; kb0 += 64) {
    const bool pf = (kb0 + 64 < SEQ);
    // T14 phase 1: issue next tile's global loads into registers NOW.
    u32x4 rk0, rv0;
    if (pf) {
      const int kb = kb0 + 64;
      rk0 = *(const u32x4*)(gK0 + (size_t)kb * DH);
      rv0 = *(const u32x4*)(gV0 + kb);
    }
    const half_t* ksrc = Ks[cur];
    const half_t* vsrc = Vs[cur];

    // QK^T swapped: A = K rows, B = Q rows. z[rt][kt][r] =
    // S[q = q0+rt*16+l16][k = kb0+kt*16+quad*4+r] - 12
    f32x4 z[2][4];
    __builtin_amdgcn_s_setprio(1);
#pragma unroll
    for (int kt = 0; kt < 4; kt++) {
      const half_t* krow = &ksrc[(kt * 16 + l16) * 64];
      half8 b0 = *(const half8*)&krow[sw0];
      half8 b1 = *(const half8*)&krow[sw1];
#pragma unroll
      for (int rt = 0; rt < 2; rt++) {
        f32x4 zz = cinit;
        zz = mfma16(b0, aqA[rt], zz);
        zz = mfma16(b1, aqB[rt], zz);
        z[rt][kt] = zz;
      }
    }
    __builtin_amdgcn_s_setprio(0);

    // softmax: exp2, f32 row-sum, packed f16 convert -> pa[rt][kt] is the
    // READY A-fragment for the K=16 PV MFMA (k = kt*16 + quad*4 + j).
    half4 pa[2][4];
#pragma unroll
    for (int rt = 0; rt < 2; rt++)
#pragma unroll
      for (int kt = 0; kt < 4; kt++) {
        f32x4 p;
#pragma unroll
        for (int r = 0; r < 4; r++) p[r] = __builtin_amdgcn_exp2f(z[rt][kt][r]);
        vsum[rt] += p;
        f16x2 lo = __builtin_amdgcn_cvt_pkrtz(p[0], p[1]);
        f16x2 hi = __builtin_amdgcn_cvt_pkrtz(p[2], p[3]);
        u32x2 w = { __builtin_bit_cast(unsigned, lo), __builtin_bit_cast(unsigned, hi) };
        pa[rt][kt] = __builtin_bit_cast(half4, w);
      }

    // PV: o[q][d] += P * V. B-frag = V[k=kt*16+quad*4+j][d=dt*16+l16], a
    // half4 from swizzled Vs (V^T rows d): phys = row*64 +
    // ((chunk ^ (row&7))*8) + within, chunk = kt*2 + (quad>>1).
    __builtin_amdgcn_s_setprio(1);
#pragma unroll
    for (int dt = 0; dt < 4; dt++) {
      const int row = dt * 16 + l16;
      const half_t* vrow = &vsrc[row * 64 + (quad & 1) * 4];
#pragma unroll
      for (int kt = 0; kt < 4; kt++) {
        half4 bv = *(const half4*)&vrow[((kt * 2 + (quad >> 1)) ^ (l16 & 7)) * 8];
#pragma unroll
        for (int rt = 0; rt < 2; rt++)
          o[rt][dt] = mfma16k16(pa[rt][kt], bv, o[rt][dt]);
      }
    }
    __builtin_amdgcn_s_setprio(0);

    // T14 phase 2: vmcnt wait (first use of rk/rv) lands HERE, after compute.
    if (pf) {
      const int nxt = cur ^ 1;
      *(u32x4*)&Ks[nxt][tid * 8] = rk0;
      *(u32x4*)&Vs[nxt][tid * 8] = rv0;
    }
    __syncthreads();  // lgkm drain + buffer handoff
    cur ^= 1;
  }

  // row sums: lane has partial sum for q = q0+rt*16+l16 over its k subset;
  // reduce across quads (lane bits 4,5), then fetch per-output-row inverse.
  float linv[2][4];
#pragma unroll
  for (int rt = 0; rt < 2; rt++) {
    float s = (vsum[rt][0] + vsum[rt][1]) + (vsum[rt][2] + vsum[rt][3]);
    s += __shfl_xor(s, 16);
    s += __shfl_xor(s, 32);
#pragma unroll
    for (int r = 0; r < 4; r++) linv[rt][r] = 1.f / __shfl(s, quad * 4 + r);
  }
#pragma unroll
  for (int rt = 0; rt < 2; rt++)
#pragma unroll
    for (int dt = 0; dt < 4; dt++)
#pragma unroll
      for (int r = 0; r < 4; r++) {
        int srow = q0 + rt * 16 + quad * 4 + r;
        AO[((size_t)bb * SEQ + srow) * DM + h * DH + dt * 16 + l16] =
            (half_t)(o[rt][dt][r] * linv[rt][r]);
      }
}

// ---------------- output projection (v3: 128x128 tile, 8 waves) ----------
// Same 128x128 tile / 256-block grid as R12 but 512 threads = 8 waves
// (each wave 64m x 32n, acc[4][2] -- the proven R11 per-wave shape).
// Doubles waves/SIMD 1 -> 2 at identical staging traffic (1 A-slot +
// 1 B-slot per thread). 2-phase double-buffered pipeline unchanged.

__global__ __launch_bounds__(512)
void out_kernel(const half_t* __restrict__ AO, const half_t* __restrict__ wto,
                const float* __restrict__ bo, float* __restrict__ out) {
  const int tid = threadIdx.x;
  const int wid = tid >> 6, lane = tid & 63;   // wid 0..7
  const int l16 = lane & 15, quad = lane >> 4;
  const int m0 = blockIdx.y * 128, n0 = blockIdx.x * 128;
  // As0 | As1 | Bs0 | Bs1 (8KB each)
  __shared__ __align__(16) char smem[32768];
  f32x4 acc[4][2] = {};
  const int wrow = (wid >> 2) * 64, wcol = (wid & 3) * 32;

  // staging: 512 threads, 1 A-slot + 1 B-slot each (512 slots = 128 rows x 4)
  const int ar = tid >> 2, ab = (tid & 3) ^ ((ar >> 1) & 3);
  const int swz = (l16 >> 1) & 3;

  // prologue: stage k0=0 into buffer 0
  {
    half_t* As = (half_t*)smem;
    half_t* Bs = (half_t*)(smem + 16384);
    gl2lds16(&AO[(size_t)(m0 + ar) * DM + ab * 8], &As[tid * 8]);
    gl2lds16(&wto[(size_t)(n0 + ar) * DM + ab * 8], &Bs[tid * 8]);
  }
  __syncthreads();

  int cur = 0;
  for (int k0 = 0; k0 < DM; k0 += 32) {
    if (k0 + 32 < DM) {
      half_t* Asn = (half_t*)(smem + (cur ^ 1) * 8192);
      half_t* Bsn = (half_t*)(smem + 16384 + (cur ^ 1) * 8192);
      const int kn = k0 + 32;
      gl2lds16(&AO[(size_t)(m0 + ar) * DM + kn + ab * 8], &Asn[tid * 8]);
      gl2lds16(&wto[(size_t)(n0 + ar) * DM + kn + ab * 8], &Bsn[tid * 8]);
    }
    const half_t* Asc = (const half_t*)(smem + cur * 8192);
    const half_t* Bsc = (const half_t*)(smem + 16384 + cur * 8192);
    half8 a[4], b[2];
#pragma unroll
    for (int rt = 0; rt < 4; rt++)
      a[rt] = *(const half8*)&Asc[((wrow + rt * 16 + l16) * 4 + (quad ^ swz)) * 8];
#pragma unroll
    for (int ct = 0; ct < 2; ct++)
      b[ct] = *(const half8*)&Bsc[((wcol + ct * 16 + l16) * 4 + (quad ^ swz)) * 8];
#pragma unroll
    for (int rt = 0; rt < 4; rt++)
#pragma unroll
      for (int ct = 0; ct < 2; ct++)
        acc[rt][ct] = mfma16(a[rt], b[ct], acc[rt][ct]);
    __syncthreads();
    cur ^= 1;
  }
  float bv2[2];
#pragma unroll
  for (int ct = 0; ct < 2; ct++) bv2[ct] = bo[n0 + wcol + ct * 16 + l16];
#pragma unroll
  for (int rt = 0; rt < 4; rt++)
#pragma unroll
    for (int r = 0; r < 4; r++) {
      int m = m0 + wrow + rt * 16 + quad * 4 + r;
#pragma unroll
      for (int ct = 0; ct < 2; ct++)
        out[(size_t)m * DM + n0 + wcol + ct * 16 + l16] = acc[rt][ct][r] + bv2[ct];
    }
}

// ---------------- launch ----------------

extern "C" void kernel_launch(void* const* d_in, const int* in_sizes, int n_in,
                              void* d_out, int out_size, void* d_ws, size_t ws_size,
                              hipStream_t stream) {
  (void)in_sizes; (void)n_in; (void)out_size; (void)ws_size;
  const float* x  = (const float*)d_in[0];
  const float* wq = (const float*)d_in[1];
  const float* bq = (const float*)d_in[2];
  const float* wk = (const float*)d_in[3];
  const float* bk = (const float*)d_in[4];
  const float* wv = (const float*)d_in[5];
  const float* bv = (const float*)d_in[6];
  const float* wo = (const float*)d_in[7];
  const float* bo = (const float*)d_in[8];
  char* ws = (char*)d_ws;
  const size_t MB = 1u << 20;
  // xh and AO share [0,8) MB: xh dead after qkv, AO born after attn.
  half_t* xh  = (half_t*)(ws + 0);
  half_t* AO  = (half_t*)(ws + 0);
  half_t* wtq = (half_t*)(ws + 8 * MB);
  half_t* wtk = (half_t*)(ws + 10 * MB);
  half_t* wtv = (half_t*)(ws + 12 * MB);
  half_t* wto = (half_t*)(ws + 14 * MB);
  float*  st  = (float*)(ws + 16 * MB);
  float*  ctb = (float*)(ws + 16 * MB + 256 * 1024);
  half_t* Qh  = (half_t*)(ws + 17 * MB);
  half_t* Kh  = (half_t*)(ws + 25 * MB);
  half_t* Vt  = (half_t*)(ws + 33 * MB);
  float* out = (float*)d_out;

  prep_kernel<<<8448, 256, 0, stream>>>(x, wq, wk, wv, wo, xh, wtq, wtk, wtv, wto, st, ctb);
  qkv_kernel<<<dim3(8, 32, 3), 256, 0, stream>>>(xh, wtq, wtk, wtv, bq, bk, bv, st, ctb, Qh, Kh, Vt);
  attn_kernel<<<256, 512, 0, stream>>>(Qh, Kh, Vt, AO);
  out_kernel<<<dim3(8, 32), 512, 0, stream>>>(AO, wto, bo, out);
}